// Round 6
// baseline (57.473 us; speedup 1.0000x reference)
//
#include <hip/hip_runtime.h>
#include <math.h>

// HSTU positional encoder:
//   out[t,:] = emb[t,:] * sqrt(D) + pos_weight[clip(pos),:]
//   pos(t) = min(len[b],P-1) - (t - off[b]), clipped to [0, P-1]
//
// R6: R5's position-window decomposition (block w stages wt rows
// [w*CT, w*CT+CT) to LDS once, applies to the matching strip of all 16
// sequences) + manual 4-wide load batching across sequences. R5 compiled
// to VGPR_Count=8 => ~1 outstanding load/thread, latency-exposed
// (VALUBusy 2%, 78% of path ceiling). Named ev0..ev3 registers force 4
// independent global loads in flight before the FMA+store group.

constexpr int D_DIM = 512;
constexpr int D4 = D_DIM / 4;    // 128 f32x4 per row
constexpr int CT = 4;            // positions (wt rows) per window/block
constexpr int MAXB = 16;

typedef float f32x4 __attribute__((ext_vector_type(4)));

__global__ __launch_bounds__(512, 4)
void hstu_pos_enc_win(const int* __restrict__ seq_lengths,
                      const int* __restrict__ seq_offsets,
                      const float* __restrict__ emb,
                      const float* __restrict__ wt,
                      float* __restrict__ out,
                      int nseq, int maxpos, float alpha)
{
    __shared__ f32x4 lds[CT * D4];          // 4 rows x 2 KB = 8 KB

    const f32x4* __restrict__ emb4 = reinterpret_cast<const f32x4*>(emb);
    const f32x4* __restrict__ wt4  = reinterpret_cast<const f32x4*>(wt);
    f32x4* __restrict__ out4       = reinterpret_cast<f32x4*>(out);

    const int p0 = (int)blockIdx.x * CT;    // first position of this window

    // Per-sequence token range whose (clipped) position falls in the window.
    int phi[MAXB], cnt[MAXB], t00[MAXB];
    int any = 0;
#pragma unroll
    for (int b = 0; b < MAXB; ++b) {
        int len  = (b < nseq) ? seq_lengths[b] : 0;
        int off  = (b < nseq) ? seq_offsets[b] : 0;
        int high = min(len, maxpos - 1);
        int pmin = high - len + 1;          // lowest unclipped position
        int lo   = (p0 == 0) ? pmin : max(p0, pmin);  // w0 takes clipped tail
        int hi   = min(p0 + CT - 1, high);
        phi[b] = hi;
        cnt[b] = hi - lo + 1;               // <=0 -> no tokens here
        t00[b] = off + high - hi;           // token with j==0 (pos==hi)
        any |= (hi >= lo) ? 1 : 0;
    }
    if (!any) return;                       // window above all sequences

    // Stage wt rows [p0, p0+CT) once (clamped to table size).
    int nstage = min(CT, maxpos - p0) * D4;
    for (int s = (int)threadIdx.x; s < nstage; s += 512)
        lds[s] = wt4[p0 * D4 + s];
    __syncthreads();

    const int lt = __builtin_amdgcn_readfirstlane((int)threadIdx.x >> 7);
    const int c4 = (int)threadIdx.x & (D4 - 1);

    // Main pass: j == lt (covers cnt <= CT, the universal case here).
    // 4 sequences batched -> 4 independent global loads in flight.
#pragma unroll
    for (int bb = 0; bb < MAXB; bb += 4) {
        bool a0, a1, a2, a3;
        int  t0_, t1_, t2_, t3_, r0, r1, r2, r3;
        f32x4 e0, e1, e2, e3;

        a0 = (lt < cnt[bb + 0]); t0_ = t00[bb + 0] + lt;
        r0 = max(phi[bb + 0] - lt, p0) - p0;
        a1 = (lt < cnt[bb + 1]); t1_ = t00[bb + 1] + lt;
        r1 = max(phi[bb + 1] - lt, p0) - p0;
        a2 = (lt < cnt[bb + 2]); t2_ = t00[bb + 2] + lt;
        r2 = max(phi[bb + 2] - lt, p0) - p0;
        a3 = (lt < cnt[bb + 3]); t3_ = t00[bb + 3] + lt;
        r3 = max(phi[bb + 3] - lt, p0) - p0;

        if (a0) e0 = emb4[t0_ * D4 + c4];
        if (a1) e1 = emb4[t1_ * D4 + c4];
        if (a2) e2 = emb4[t2_ * D4 + c4];
        if (a3) e3 = emb4[t3_ * D4 + c4];

        if (a0) {
            f32x4 wv = lds[r0 * D4 + c4]; f32x4 o;
            o.x = fmaf(e0.x, alpha, wv.x); o.y = fmaf(e0.y, alpha, wv.y);
            o.z = fmaf(e0.z, alpha, wv.z); o.w = fmaf(e0.w, alpha, wv.w);
            out4[t0_ * D4 + c4] = o;
        }
        if (a1) {
            f32x4 wv = lds[r1 * D4 + c4]; f32x4 o;
            o.x = fmaf(e1.x, alpha, wv.x); o.y = fmaf(e1.y, alpha, wv.y);
            o.z = fmaf(e1.z, alpha, wv.z); o.w = fmaf(e1.w, alpha, wv.w);
            out4[t1_ * D4 + c4] = o;
        }
        if (a2) {
            f32x4 wv = lds[r2 * D4 + c4]; f32x4 o;
            o.x = fmaf(e2.x, alpha, wv.x); o.y = fmaf(e2.y, alpha, wv.y);
            o.z = fmaf(e2.z, alpha, wv.z); o.w = fmaf(e2.w, alpha, wv.w);
            out4[t2_ * D4 + c4] = o;
        }
        if (a3) {
            f32x4 wv = lds[r3 * D4 + c4]; f32x4 o;
            o.x = fmaf(e3.x, alpha, wv.x); o.y = fmaf(e3.y, alpha, wv.y);
            o.z = fmaf(e3.z, alpha, wv.z); o.w = fmaf(e3.w, alpha, wv.w);
            out4[t3_ * D4 + c4] = o;
        }
    }

    // Clip-tail fallback: only taken when cnt[b] > CT (w==0 with
    // len > maxpos-1; all those tokens map to LDS row 0). Never hit in
    // this bench's data but required for correctness.
#pragma unroll
    for (int b = 0; b < MAXB; ++b) {
        for (int j0 = CT; j0 < cnt[b]; j0 += CT) {
            int j = j0 + lt;
            if (j < cnt[b]) {
                int t   = t00[b] + j;
                int row = max(phi[b] - j, p0) - p0;
                f32x4 ev = emb4[t * D4 + c4];
                f32x4 wv = lds[row * D4 + c4];
                f32x4 o;
                o.x = fmaf(ev.x, alpha, wv.x); o.y = fmaf(ev.y, alpha, wv.y);
                o.z = fmaf(ev.z, alpha, wv.z); o.w = fmaf(ev.w, alpha, wv.w);
                out4[t * D4 + c4] = o;
            }
        }
    }
}

// Generic fallback for nseq > MAXB (not hit in this bench).
__global__ void hstu_pos_enc_generic(const int* __restrict__ seq_lengths,
                                     const int* __restrict__ seq_offsets,
                                     const float* __restrict__ emb,
                                     const float* __restrict__ wt,
                                     float* __restrict__ out,
                                     int nelem4, int nseq, int maxpos,
                                     float alpha)
{
    const f32x4* __restrict__ emb4 = reinterpret_cast<const f32x4*>(emb);
    const f32x4* __restrict__ wt4  = reinterpret_cast<const f32x4*>(wt);
    f32x4* __restrict__ out4       = reinterpret_cast<f32x4*>(out);

    int stride = gridDim.x * blockDim.x;
    for (int idx = blockIdx.x * blockDim.x + threadIdx.x;
         idx < nelem4; idx += stride) {
        int tok = idx >> 7;
        int c4  = idx & (D4 - 1);
        int seg = 0;
        for (int b = 1; b < nseq; ++b)
            if (seq_offsets[b] <= tok) seg = b;
        int start = seq_offsets[seg];
        int high  = min(seq_lengths[seg], maxpos - 1);
        int pos   = min(max(high - (tok - start), 0), maxpos - 1);
        f32x4 e = emb4[idx];
        f32x4 w = wt4[pos * D4 + c4];
        f32x4 o;
        o.x = fmaf(e.x, alpha, w.x);
        o.y = fmaf(e.y, alpha, w.y);
        o.z = fmaf(e.z, alpha, w.z);
        o.w = fmaf(e.w, alpha, w.w);
        out4[idx] = o;
    }
}

extern "C" void kernel_launch(void* const* d_in, const int* in_sizes, int n_in,
                              void* d_out, int out_size, void* d_ws, size_t ws_size,
                              hipStream_t stream)
{
    // Inputs (setup_inputs order):
    // 0: max_seq_len scalar, 1: seq_lengths[B], 2: seq_offsets[B+1],
    // 3: seq_embeddings[TOTAL,D] f32, 4: pos_weight[P,D] f32
    const int*   seq_lengths = (const int*)d_in[1];
    const int*   seq_offsets = (const int*)d_in[2];
    const float* emb         = (const float*)d_in[3];
    const float* wt          = (const float*)d_in[4];
    float*       out         = (float*)d_out;

    int B     = in_sizes[1];
    int P     = in_sizes[4] / D_DIM;
    int total = in_sizes[3] / D_DIM;
    float alpha = sqrtf((float)D_DIM);

    if (B <= MAXB) {
        int nwin = (P + CT - 1) / CT;
        hstu_pos_enc_win<<<dim3(nwin), dim3(512), 0, stream>>>(
            seq_lengths, seq_offsets, emb, wt, out, B, P, alpha);
    } else {
        int nelem4 = total * D4;
        int grid = (nelem4 + 255) / 256;
        if (grid > 2048) grid = 2048;
        hstu_pos_enc_generic<<<dim3(grid), dim3(256), 0, stream>>>(
            seq_lengths, seq_offsets, emb, wt, out, nelem4, B, P, alpha);
    }
}

// Round 7
// 46.485 us; speedup vs baseline: 1.2364x; 1.2364x over previous
//
#include <hip/hip_runtime.h>
#include <math.h>

// HSTU positional encoder:
//   out[t,:] = emb[t,:] * sqrt(D) + pos_weight[clip(pos),:]
//   pos(t) = min(len[b],P-1) - (t - off[b]), clipped to [0, P-1]
//
// R7: R5's position-window decomposition (block w stages wt rows
// [w*CT,w*CT+CT) into LDS once, applies them to the matching strip of
// all 16 sequences) with the CACHE POLICY fixed:
//   - emb: REGULAR load  -> allocates in LLC; emb(134MB)+wt(16MB) < 256MB
//     LLC, so steady-state replays serve emb from LLC (R1 showed regular
//     stores thrash it; R3/R5 nt-loads kept it out of LLC entirely).
//   - out: NONTEMPORAL store -> no-allocate, leaves LLC to emb. R3 proved
//     nt-store keeps WRITE at exactly 131MB on this contiguous layout.
// R6's manual 4-wide batching regressed (latency is not the limiter) —
// reverted to R5's simple loop.

constexpr int D_DIM = 512;
constexpr int D4 = D_DIM / 4;    // 128 f32x4 per row
constexpr int CT = 4;            // positions (wt rows) per window/block
constexpr int MAXB = 16;

typedef float f32x4 __attribute__((ext_vector_type(4)));

__global__ __launch_bounds__(512, 4)
void hstu_pos_enc_win(const int* __restrict__ seq_lengths,
                      const int* __restrict__ seq_offsets,
                      const float* __restrict__ emb,
                      const float* __restrict__ wt,
                      float* __restrict__ out,
                      int nseq, int maxpos, float alpha)
{
    __shared__ f32x4 lds[CT * D4];          // 4 rows x 2 KB = 8 KB

    const f32x4* __restrict__ emb4 = reinterpret_cast<const f32x4*>(emb);
    const f32x4* __restrict__ wt4  = reinterpret_cast<const f32x4*>(wt);
    f32x4* __restrict__ out4       = reinterpret_cast<f32x4*>(out);

    const int p0 = (int)blockIdx.x * CT;    // first position of this window

    // Per-sequence token range whose (clipped) position falls in the window.
    int phi[MAXB], cnt[MAXB], t00[MAXB];
    int any = 0;
#pragma unroll
    for (int b = 0; b < MAXB; ++b) {
        int len  = (b < nseq) ? seq_lengths[b] : 0;
        int off  = (b < nseq) ? seq_offsets[b] : 0;
        int high = min(len, maxpos - 1);
        int pmin = high - len + 1;          // lowest unclipped position
        int lo   = (p0 == 0) ? pmin : max(p0, pmin);  // w0 takes clipped tail
        int hi   = min(p0 + CT - 1, high);
        phi[b] = hi;
        cnt[b] = hi - lo + 1;               // <=0 -> no tokens here
        t00[b] = off + high - hi;           // token with j==0 (pos==hi)
        any |= (hi >= lo) ? 1 : 0;
    }
    if (!any) return;                       // window above all sequences

    // Stage wt rows [p0, p0+CT) once (clamped to table size).
    int nstage = min(CT, maxpos - p0) * D4;
    for (int s = (int)threadIdx.x; s < nstage; s += 512)
        lds[s] = wt4[p0 * D4 + s];
    __syncthreads();

    const int lt = __builtin_amdgcn_readfirstlane((int)threadIdx.x >> 7);
    const int c4 = (int)threadIdx.x & (D4 - 1);

#pragma unroll
    for (int b = 0; b < MAXB; ++b) {
        int count = cnt[b];
        for (int j0 = 0; j0 < count; j0 += CT) {
            int j = j0 + lt;
            if (j < count) {
                int t   = t00[b] + j;
                int p   = phi[b] - j;               // unclipped position
                int row = max(p, p0) - p0;          // LDS row (handles clip)
                f32x4 ev = emb4[t * D4 + c4];       // regular: LLC-resident
                f32x4 wv = lds[row * D4 + c4];
                f32x4 o;
                o.x = fmaf(ev.x, alpha, wv.x);
                o.y = fmaf(ev.y, alpha, wv.y);
                o.z = fmaf(ev.z, alpha, wv.z);
                o.w = fmaf(ev.w, alpha, wv.w);
                __builtin_nontemporal_store(o, &out4[t * D4 + c4]);
            }
        }
    }
}

// Generic fallback for nseq > MAXB (not hit in this bench).
__global__ void hstu_pos_enc_generic(const int* __restrict__ seq_lengths,
                                     const int* __restrict__ seq_offsets,
                                     const float* __restrict__ emb,
                                     const float* __restrict__ wt,
                                     float* __restrict__ out,
                                     int nelem4, int nseq, int maxpos,
                                     float alpha)
{
    const f32x4* __restrict__ emb4 = reinterpret_cast<const f32x4*>(emb);
    const f32x4* __restrict__ wt4  = reinterpret_cast<const f32x4*>(wt);
    f32x4* __restrict__ out4       = reinterpret_cast<f32x4*>(out);

    int stride = gridDim.x * blockDim.x;
    for (int idx = blockIdx.x * blockDim.x + threadIdx.x;
         idx < nelem4; idx += stride) {
        int tok = idx >> 7;
        int c4  = idx & (D4 - 1);
        int seg = 0;
        for (int b = 1; b < nseq; ++b)
            if (seq_offsets[b] <= tok) seg = b;
        int start = seq_offsets[seg];
        int high  = min(seq_lengths[seg], maxpos - 1);
        int pos   = min(max(high - (tok - start), 0), maxpos - 1);
        f32x4 e = emb4[idx];
        f32x4 w = wt4[pos * D4 + c4];
        f32x4 o;
        o.x = fmaf(e.x, alpha, w.x);
        o.y = fmaf(e.y, alpha, w.y);
        o.z = fmaf(e.z, alpha, w.z);
        o.w = fmaf(e.w, alpha, w.w);
        out4[idx] = o;
    }
}

extern "C" void kernel_launch(void* const* d_in, const int* in_sizes, int n_in,
                              void* d_out, int out_size, void* d_ws, size_t ws_size,
                              hipStream_t stream)
{
    // Inputs (setup_inputs order):
    // 0: max_seq_len scalar, 1: seq_lengths[B], 2: seq_offsets[B+1],
    // 3: seq_embeddings[TOTAL,D] f32, 4: pos_weight[P,D] f32
    const int*   seq_lengths = (const int*)d_in[1];
    const int*   seq_offsets = (const int*)d_in[2];
    const float* emb         = (const float*)d_in[3];
    const float* wt          = (const float*)d_in[4];
    float*       out         = (float*)d_out;

    int B     = in_sizes[1];
    int P     = in_sizes[4] / D_DIM;
    int total = in_sizes[3] / D_DIM;
    float alpha = sqrtf((float)D_DIM);

    if (B <= MAXB) {
        int nwin = (P + CT - 1) / CT;
        hstu_pos_enc_win<<<dim3(nwin), dim3(512), 0, stream>>>(
            seq_lengths, seq_offsets, emb, wt, out, B, P, alpha);
    } else {
        int nelem4 = total * D4;
        int grid = (nelem4 + 255) / 256;
        if (grid > 2048) grid = 2048;
        hstu_pos_enc_generic<<<dim3(grid), dim3(256), 0, stream>>>(
            seq_lengths, seq_offsets, emb, wt, out, nelem4, B, P, alpha);
    }
}

// Round 8
// 46.296 us; speedup vs baseline: 1.2414x; 1.0041x over previous
//
#include <hip/hip_runtime.h>
#include <math.h>

// HSTU positional encoder:
//   out[t,:] = emb[t,:] * sqrt(D) + pos_weight[clip(pos),:]
//   pos(t) = min(len[b],P-1) - (t - off[b]), clipped to [0, P-1]
//
// R8: R7 (position-window LDS staging + regular emb load + nt out store)
// with 256-thread blocks. R7's 512-thread blocks gave 1075 active blocks
// x 8 waves = 8600 waves > 8192-wave machine capacity -> ~51 blocks ran
// in a second, nearly-empty round (the ~3.5us gap to the 43us roofline).
// 256-thread blocks -> 4300 active waves, fully co-resident, no tail.
// TR = 256/128 = 2 token-rows per pass; 2 passes cover the CT=4 window.

constexpr int D_DIM = 512;
constexpr int D4 = D_DIM / 4;    // 128 f32x4 per row
constexpr int CT = 4;            // positions (wt rows) per window/block
constexpr int TR = 2;            // token-rows covered per pass (256/128)
constexpr int MAXB = 16;

typedef float f32x4 __attribute__((ext_vector_type(4)));

__global__ __launch_bounds__(256, 4)
void hstu_pos_enc_win(const int* __restrict__ seq_lengths,
                      const int* __restrict__ seq_offsets,
                      const float* __restrict__ emb,
                      const float* __restrict__ wt,
                      float* __restrict__ out,
                      int nseq, int maxpos, float alpha)
{
    __shared__ f32x4 lds[CT * D4];          // 4 rows x 2 KB = 8 KB

    const f32x4* __restrict__ emb4 = reinterpret_cast<const f32x4*>(emb);
    const f32x4* __restrict__ wt4  = reinterpret_cast<const f32x4*>(wt);
    f32x4* __restrict__ out4       = reinterpret_cast<f32x4*>(out);

    const int p0 = (int)blockIdx.x * CT;    // first position of this window

    // Per-sequence token range whose (clipped) position falls in the window.
    int phi[MAXB], cnt[MAXB], t00[MAXB];
    int any = 0;
#pragma unroll
    for (int b = 0; b < MAXB; ++b) {
        int len  = (b < nseq) ? seq_lengths[b] : 0;
        int off  = (b < nseq) ? seq_offsets[b] : 0;
        int high = min(len, maxpos - 1);
        int pmin = high - len + 1;          // lowest unclipped position
        int lo   = (p0 == 0) ? pmin : max(p0, pmin);  // w0 takes clipped tail
        int hi   = min(p0 + CT - 1, high);
        phi[b] = hi;
        cnt[b] = hi - lo + 1;               // <=0 -> no tokens here
        t00[b] = off + high - hi;           // token with j==0 (pos==hi)
        any |= (hi >= lo) ? 1 : 0;
    }
    if (!any) return;                       // window above all sequences

    // Stage wt rows [p0, p0+CT) once (clamped to table size).
    int nstage = min(CT, maxpos - p0) * D4;
    for (int s = (int)threadIdx.x; s < nstage; s += 256)
        lds[s] = wt4[p0 * D4 + s];
    __syncthreads();

    const int lt = __builtin_amdgcn_readfirstlane((int)threadIdx.x >> 7);
    const int c4 = (int)threadIdx.x & (D4 - 1);

#pragma unroll
    for (int b = 0; b < MAXB; ++b) {
        int count = cnt[b];
        for (int j0 = 0; j0 < count; j0 += TR) {
            int j = j0 + lt;
            if (j < count) {
                int t   = t00[b] + j;
                int p   = phi[b] - j;               // unclipped position
                int row = max(p, p0) - p0;          // LDS row (handles clip)
                f32x4 ev = emb4[t * D4 + c4];       // regular: cache-resident
                f32x4 wv = lds[row * D4 + c4];
                f32x4 o;
                o.x = fmaf(ev.x, alpha, wv.x);
                o.y = fmaf(ev.y, alpha, wv.y);
                o.z = fmaf(ev.z, alpha, wv.z);
                o.w = fmaf(ev.w, alpha, wv.w);
                __builtin_nontemporal_store(o, &out4[t * D4 + c4]);
            }
        }
    }
}

// Generic fallback for nseq > MAXB (not hit in this bench).
__global__ void hstu_pos_enc_generic(const int* __restrict__ seq_lengths,
                                     const int* __restrict__ seq_offsets,
                                     const float* __restrict__ emb,
                                     const float* __restrict__ wt,
                                     float* __restrict__ out,
                                     int nelem4, int nseq, int maxpos,
                                     float alpha)
{
    const f32x4* __restrict__ emb4 = reinterpret_cast<const f32x4*>(emb);
    const f32x4* __restrict__ wt4  = reinterpret_cast<const f32x4*>(wt);
    f32x4* __restrict__ out4       = reinterpret_cast<f32x4*>(out);

    int stride = gridDim.x * blockDim.x;
    for (int idx = blockIdx.x * blockDim.x + threadIdx.x;
         idx < nelem4; idx += stride) {
        int tok = idx >> 7;
        int c4  = idx & (D4 - 1);
        int seg = 0;
        for (int b = 1; b < nseq; ++b)
            if (seq_offsets[b] <= tok) seg = b;
        int start = seq_offsets[seg];
        int high  = min(seq_lengths[seg], maxpos - 1);
        int pos   = min(max(high - (tok - start), 0), maxpos - 1);
        f32x4 e = emb4[idx];
        f32x4 w = wt4[pos * D4 + c4];
        f32x4 o;
        o.x = fmaf(e.x, alpha, w.x);
        o.y = fmaf(e.y, alpha, w.y);
        o.z = fmaf(e.z, alpha, w.z);
        o.w = fmaf(e.w, alpha, w.w);
        out4[idx] = o;
    }
}

extern "C" void kernel_launch(void* const* d_in, const int* in_sizes, int n_in,
                              void* d_out, int out_size, void* d_ws, size_t ws_size,
                              hipStream_t stream)
{
    // Inputs (setup_inputs order):
    // 0: max_seq_len scalar, 1: seq_lengths[B], 2: seq_offsets[B+1],
    // 3: seq_embeddings[TOTAL,D] f32, 4: pos_weight[P,D] f32
    const int*   seq_lengths = (const int*)d_in[1];
    const int*   seq_offsets = (const int*)d_in[2];
    const float* emb         = (const float*)d_in[3];
    const float* wt          = (const float*)d_in[4];
    float*       out         = (float*)d_out;

    int B     = in_sizes[1];
    int P     = in_sizes[4] / D_DIM;
    int total = in_sizes[3] / D_DIM;
    float alpha = sqrtf((float)D_DIM);

    if (B <= MAXB) {
        int nwin = (P + CT - 1) / CT;
        hstu_pos_enc_win<<<dim3(nwin), dim3(256), 0, stream>>>(
            seq_lengths, seq_offsets, emb, wt, out, B, P, alpha);
    } else {
        int nelem4 = total * D4;
        int grid = (nelem4 + 255) / 256;
        if (grid > 2048) grid = 2048;
        hstu_pos_enc_generic<<<dim3(grid), dim3(256), 0, stream>>>(
            seq_lengths, seq_offsets, emb, wt, out, nelem4, B, P, alpha);
    }
}